// Round 8
// baseline (220.601 us; speedup 1.0000x reference)
//
#include <hip/hip_runtime.h>

#define LOG2E 1.44269504088896340736f

// ds_swizzle BitMode: src_lane = ((lane & and) | or) ^ xor (per 32-lane half)
// imm = (xor<<10) | (or<<5) | and     — masks below proven in R2.
#define SWZ(v, imm) __int_as_float(__builtin_amdgcn_ds_swizzle(__float_as_int(v), (imm)))

// R2-proven 16-lane layout: lr=tid&15, q=(lr>>2)&3 gate {i,f,g,o}, k=lr&3 unit
// (3 dups 2). NEW: each thread carries TWO rows (A,B) with software-interleaved
// phases so every LDS wait has guaranteed independent work (B's compute, next
// step's xW FMAs) behind it. 256 blocks x 256 thr = 1024 waves, 32 rows/block.
__global__ __launch_bounds__(256, 1)
void lstm_ab_kernel(const float* __restrict__ X,    // [8192,512,16]
                    const float* __restrict__ Wg,   // [16,12]
                    const float* __restrict__ Ug,   // [3,12]
                    const float* __restrict__ bg,   // [12]
                    const float* __restrict__ Wd,   // [3]
                    const float* __restrict__ bd,   // [1]
                    float* __restrict__ out)        // [8192]
{
    constexpr int T = 512;
    const int tid = threadIdx.x;
    const int lr  = tid & 15;         // lane within row group
    const int q   = (lr >> 2) & 3;    // gate: 0=i,1=f,2=g,3=o (Keras order)
    const int k   = lr & 3;           // unit (3 == duplicate of 2)
    const int kk  = (k == 3) ? 2 : k;
    const int col = q * 3 + kk;
    const int rA  = blockIdx.x * 32 + (tid >> 4);
    const int rB  = rA + 16;

    float w[16];
#pragma unroll
    for (int f = 0; f < 16; ++f) w[f] = Wg[f * 12 + col];
    const float u0 = Ug[col], u1 = Ug[12 + col], u2 = Ug[24 + col];
    const float bias = bg[col];
    const float wd0 = Wd[0], wd1 = Wd[1], wd2 = Wd[2], bdv = bd[0];

    // act(z) = pa * rcp(1 + exp2(z*pre)) + pb ; tanh for q==2 (g)
    const bool is_g = (q == 2);
    const float pre = is_g ? (-2.0f * LOG2E) : (-LOG2E);
    const float pa  = is_g ? 2.0f : 1.0f;
    const float pb  = is_g ? -1.0f : 0.0f;

    float cA = 0.f, h0A = 0.f, h1A = 0.f, h2A = 0.f;
    float cB = 0.f, h0B = 0.f, h1B = 0.f, h2B = 0.f;

    const float4* XA = reinterpret_cast<const float4*>(X) + (size_t)rA * (T * 4);
    const float4* XB = reinterpret_cast<const float4*>(X) + (size_t)rB * (T * 4);

    // 4-slot prefetch pipeline per row (statically indexed after unroll)
    float4 xbA[4][4], xbB[4][4];
#pragma unroll
    for (int s = 0; s < 4; ++s)
#pragma unroll
        for (int p = 0; p < 4; ++p) {
            xbA[s][p] = XA[s * 4 + p];
            xbB[s][p] = XB[s * 4 + p];
        }

    // rolling xW pre-activations (computed one step ahead, off critical path)
    float zxA, zxB;
    {
        const float4 a0 = xbA[0][0], a1 = xbA[0][1], a2 = xbA[0][2], a3 = xbA[0][3];
        const float4 b0 = xbB[0][0], b1 = xbB[0][1], b2 = xbB[0][2], b3 = xbB[0][3];
        const float xvA[16] = {a0.x,a0.y,a0.z,a0.w, a1.x,a1.y,a1.z,a1.w,
                               a2.x,a2.y,a2.z,a2.w, a3.x,a3.y,a3.z,a3.w};
        const float xvB[16] = {b0.x,b0.y,b0.z,b0.w, b1.x,b1.y,b1.z,b1.w,
                               b2.x,b2.y,b2.z,b2.w, b3.x,b3.y,b3.z,b3.w};
        zxA = bias; zxB = bias;
#pragma unroll
        for (int f = 0; f < 16; ++f) {
            zxA = fmaf(xvA[f], w[f], zxA);
            zxB = fmaf(xvB[f], w[f], zxB);
        }
    }

    for (int t0 = 0; t0 < T; t0 += 4) {
#pragma unroll
        for (int s = 0; s < 4; ++s) {
            // ---- (a) A pre-round: z, act, issue 4 gathers ----
            float zA = fmaf(h0A, u0, zxA);
            zA = fmaf(h1A, u1, zA);
            zA = fmaf(h2A, u2, zA);
            const float eA   = __builtin_amdgcn_exp2f(zA * pre);
            const float valA = fmaf(pa, __builtin_amdgcn_rcpf(1.0f + eA), pb);
            const float ivA = SWZ(valA, 0x013);
            const float fvA = SWZ(valA, 0x093);
            const float gvA = SWZ(valA, 0x113);
            const float ovA = SWZ(valA, 0x193);

            // ---- (b) B pre-round ----
            float zB = fmaf(h0B, u0, zxB);
            zB = fmaf(h1B, u1, zB);
            zB = fmaf(h2B, u2, zB);
            const float eB   = __builtin_amdgcn_exp2f(zB * pre);
            const float valB = fmaf(pa, __builtin_amdgcn_rcpf(1.0f + eB), pb);
            const float ivB = SWZ(valB, 0x013);
            const float fvB = SWZ(valB, 0x093);
            const float gvB = SWZ(valB, 0x113);
            const float ovB = SWZ(valB, 0x193);

            // ---- (f) prefetch slot s <- t0+4+s (clamped; fills waits) ----
            {
                int tn = t0 + 4 + s;
                tn = (tn < T) ? tn : (T - 1);
                const size_t o = (size_t)tn * 4;
                xbA[s][0] = XA[o + 0]; xbA[s][1] = XA[o + 1];
                xbA[s][2] = XA[o + 2]; xbA[s][3] = XA[o + 3];
                xbB[s][0] = XB[o + 0]; xbB[s][1] = XB[o + 1];
                xbB[s][2] = XB[o + 2]; xbB[s][3] = XB[o + 3];
            }

            // ---- (c) next-step xW (independent; fills A's gather wait) ----
            float nzA = bias, nzB = bias;
            {
                const float4 a0 = xbA[(s+1)&3][0], a1 = xbA[(s+1)&3][1],
                             a2 = xbA[(s+1)&3][2], a3 = xbA[(s+1)&3][3];
                const float4 b0 = xbB[(s+1)&3][0], b1 = xbB[(s+1)&3][1],
                             b2 = xbB[(s+1)&3][2], b3 = xbB[(s+1)&3][3];
                const float xvA[16] = {a0.x,a0.y,a0.z,a0.w, a1.x,a1.y,a1.z,a1.w,
                                       a2.x,a2.y,a2.z,a2.w, a3.x,a3.y,a3.z,a3.w};
                const float xvB[16] = {b0.x,b0.y,b0.z,b0.w, b1.x,b1.y,b1.z,b1.w,
                                       b2.x,b2.y,b2.z,b2.w, b3.x,b3.y,b3.z,b3.w};
#pragma unroll
                for (int f = 0; f < 16; ++f) {
                    nzA = fmaf(xvA[f], w[f], nzA);
                    nzB = fmaf(xvB[f], w[f], nzB);
                }
            }

            // ---- (d) A mid: cell update, issue 3 h-broadcasts ----
            cA = fmaf(fvA, cA, ivA * gvA);
            const float ecA = __builtin_amdgcn_exp2f(cA * (-2.0f * LOG2E));
            const float thA = fmaf(2.0f, __builtin_amdgcn_rcpf(1.0f + ecA), -1.0f);
            const float hkA = ovA * thA;
            const float nh0A = SWZ(hkA, 0x01C);
            const float nh1A = SWZ(hkA, 0x03C);
            const float nh2A = SWZ(hkA, 0x05C);

            // ---- (e) B mid ----
            cB = fmaf(fvB, cB, ivB * gvB);
            const float ecB = __builtin_amdgcn_exp2f(cB * (-2.0f * LOG2E));
            const float thB = fmaf(2.0f, __builtin_amdgcn_rcpf(1.0f + ecB), -1.0f);
            const float hkB = ovB * thB;
            const float nh0B = SWZ(hkB, 0x01C);
            const float nh1B = SWZ(hkB, 0x03C);
            const float nh2B = SWZ(hkB, 0x05C);

            // ---- (g) commit ----
            h0A = nh0A; h1A = nh1A; h2A = nh2A;
            h0B = nh0B; h1B = nh1B; h2B = nh2B;
            zxA = nzA;  zxB = nzB;
        }
    }

    if (lr == 0) {
        float accA = bdv;
        accA = fmaf(h0A, wd0, accA);
        accA = fmaf(h1A, wd1, accA);
        accA = fmaf(h2A, wd2, accA);
        const float eA = __builtin_amdgcn_exp2f(-LOG2E * accA);
        out[rA] = __builtin_amdgcn_rcpf(1.0f + eA);

        float accB = bdv;
        accB = fmaf(h0B, wd0, accB);
        accB = fmaf(h1B, wd1, accB);
        accB = fmaf(h2B, wd2, accB);
        const float eB = __builtin_amdgcn_exp2f(-LOG2E * accB);
        out[rB] = __builtin_amdgcn_rcpf(1.0f + eB);
    }
}

extern "C" void kernel_launch(void* const* d_in, const int* in_sizes, int n_in,
                              void* d_out, int out_size, void* d_ws, size_t ws_size,
                              hipStream_t stream) {
    const float* X  = (const float*)d_in[0];
    const float* W  = (const float*)d_in[1];
    const float* U  = (const float*)d_in[2];
    const float* bg = (const float*)d_in[3];
    const float* Wd = (const float*)d_in[4];
    const float* bd = (const float*)d_in[5];
    float* out = (float*)d_out;

    dim3 grid(8192 / 32);   // 256 blocks x 256 threads = 1024 waves, 2 rows/thread
    dim3 block(256);
    hipLaunchKernelGGL(lstm_ab_kernel, grid, block, 0, stream,
                       X, W, U, bg, Wd, bd, out);
}

// Round 9
// 220.589 us; speedup vs baseline: 1.0001x; 1.0001x over previous
//
#include <hip/hip_runtime.h>

#define LOG2E 1.44269504088896340736f

// ds_swizzle BitMode: src_lane = ((lane & and) | or) ^ xor (per 32-lane half)
// imm = (xor<<10) | (or<<5) | and     — masks proven in R2.
#define SWZ(v, imm) __int_as_float(__builtin_amdgcn_ds_swizzle(__float_as_int(v), (imm)))

// UNIT-OWNER layout: 4 lanes per batch row. lane k = tid&3 owns hidden unit
// kk=min(k,2) (lane 3 duplicates unit 2) and computes ALL FOUR gate columns of
// that unit locally -> no gate-gather round. Only per-step cross-lane traffic:
// 3 h-broadcast swizzles (one LDS round), masks identical to R2's proven ones
// (bits[1:0]=unit index, bits[4:2]=row -> and=0x1C keeps row, or=j picks unit).
// 16 rows/block (64 thr), 512 blocks = 512 waves; 2 waves/CU on all CUs.
__global__ __launch_bounds__(64, 1)
void lstm_unit_kernel(const float* __restrict__ X,    // [8192,512,16]
                      const float* __restrict__ Wg,   // [16,12] cols i0..2,f0..2,g0..2,o0..2
                      const float* __restrict__ Ug,   // [3,12]
                      const float* __restrict__ bg,   // [12]
                      const float* __restrict__ Wd,   // [3]
                      const float* __restrict__ bd,   // [1]
                      float* __restrict__ out)        // [8192]
{
    constexpr int T = 512;
    const int tid = threadIdx.x;      // 0..63
    const int k   = tid & 3;
    const int kk  = (k == 3) ? 2 : k;
    const int b   = blockIdx.x * 16 + (tid >> 2);

    // This lane's four gate columns (Keras order i,f,c(g),o)
    const int ci = kk, cf = 3 + kk, cg = 6 + kk, co = 9 + kk;

    float wi[16], wf[16], wgg[16], wo[16];
#pragma unroll
    for (int f = 0; f < 16; ++f) {
        const float* row = Wg + f * 12;
        wi[f] = row[ci]; wf[f] = row[cf]; wgg[f] = row[cg]; wo[f] = row[co];
    }
    float ui[3], uf[3], ug[3], uo[3];
#pragma unroll
    for (int s = 0; s < 3; ++s) {
        const float* row = Ug + s * 12;
        ui[s] = row[ci]; uf[s] = row[cf]; ug[s] = row[cg]; uo[s] = row[co];
    }
    const float bi = bg[ci], bf_ = bg[cf], bgg = bg[cg], bo = bg[co];
    const float wd0 = Wd[0], wd1 = Wd[1], wd2 = Wd[2], bdv = bd[0];

    float c = 0.f, h0 = 0.f, h1 = 0.f, h2 = 0.f;

    const float4* X4 = reinterpret_cast<const float4*>(X) + (size_t)b * (T * 4);

    // 4-step prefetch pipeline (statically indexed after unroll)
    float4 xb[4][4];
#pragma unroll
    for (int s = 0; s < 4; ++s)
#pragma unroll
        for (int p = 0; p < 4; ++p)
            xb[s][p] = X4[s * 4 + p];

    // rolling xW pre-activations for the CURRENT step (computed one step ahead)
    float zxi, zxf, zxg, zxo;
    {
        const float4 v0 = xb[0][0], v1 = xb[0][1], v2 = xb[0][2], v3 = xb[0][3];
        const float xv[16] = {v0.x,v0.y,v0.z,v0.w, v1.x,v1.y,v1.z,v1.w,
                              v2.x,v2.y,v2.z,v2.w, v3.x,v3.y,v3.z,v3.w};
        zxi = bi; zxf = bf_; zxg = bgg; zxo = bo;
#pragma unroll
        for (int f = 0; f < 16; ++f) {
            zxi = fmaf(xv[f], wi[f],  zxi);
            zxf = fmaf(xv[f], wf[f],  zxf);
            zxg = fmaf(xv[f], wgg[f], zxg);
            zxo = fmaf(xv[f], wo[f],  zxo);
        }
    }

    for (int t0 = 0; t0 < T; t0 += 4) {
#pragma unroll
        for (int s = 0; s < 4; ++s) {
            // ---- recurrent terms (consumes h broadcasts of previous step) ----
            float zi = zxi, zf = zxf, zg = zxg, zo = zxo;
            zi = fmaf(h0, ui[0], zi); zi = fmaf(h1, ui[1], zi); zi = fmaf(h2, ui[2], zi);
            zf = fmaf(h0, uf[0], zf); zf = fmaf(h1, uf[1], zf); zf = fmaf(h2, uf[2], zf);
            zg = fmaf(h0, ug[0], zg); zg = fmaf(h1, ug[1], zg); zg = fmaf(h2, ug[2], zg);
            zo = fmaf(h0, uo[0], zo); zo = fmaf(h1, uo[1], zo); zo = fmaf(h2, uo[2], zo);

            // ---- activations (4 parallel chains, all local) ----
            const float ei = __builtin_amdgcn_exp2f(zi * (-LOG2E));
            const float ef = __builtin_amdgcn_exp2f(zf * (-LOG2E));
            const float eg = __builtin_amdgcn_exp2f(zg * (-2.0f * LOG2E));
            const float eo = __builtin_amdgcn_exp2f(zo * (-LOG2E));
            const float ai = __builtin_amdgcn_rcpf(1.0f + ei);
            const float af = __builtin_amdgcn_rcpf(1.0f + ef);
            const float ag = fmaf(2.0f, __builtin_amdgcn_rcpf(1.0f + eg), -1.0f);
            const float ao = __builtin_amdgcn_rcpf(1.0f + eo);

            // ---- local cell/hidden update ----
            c = fmaf(af, c, ai * ag);
            const float ec = __builtin_amdgcn_exp2f(c * (-2.0f * LOG2E));
            const float th = fmaf(2.0f, __builtin_amdgcn_rcpf(1.0f + ec), -1.0f);
            const float hk = ao * th;

            // ---- the ONE cross-lane round: broadcast h0,h1,h2 ----
            h0 = SWZ(hk, 0x01C);
            h1 = SWZ(hk, 0x03C);
            h2 = SWZ(hk, 0x05C);

            // ---- prefetch slot s <- t0+4+s (clamped; fills waits) ----
            {
                int tn = t0 + 4 + s;
                tn = (tn < T) ? tn : (T - 1);
                const size_t o = (size_t)tn * 4;
                xb[s][0] = X4[o + 0]; xb[s][1] = X4[o + 1];
                xb[s][2] = X4[o + 2]; xb[s][3] = X4[o + 3];
            }

            // ---- next-step xW (64 independent FMAs — fills the broadcast
            //      latency; (s+1)&3 is compile-time after unroll) ----
            {
                const float4 v0 = xb[(s+1)&3][0], v1 = xb[(s+1)&3][1],
                             v2 = xb[(s+1)&3][2], v3 = xb[(s+1)&3][3];
                const float xv[16] = {v0.x,v0.y,v0.z,v0.w, v1.x,v1.y,v1.z,v1.w,
                                      v2.x,v2.y,v2.z,v2.w, v3.x,v3.y,v3.z,v3.w};
                float ni = bi, nf = bf_, ng = bgg, no_ = bo;
#pragma unroll
                for (int f = 0; f < 16; ++f) {
                    ni  = fmaf(xv[f], wi[f],  ni);
                    nf  = fmaf(xv[f], wf[f],  nf);
                    ng  = fmaf(xv[f], wgg[f], ng);
                    no_ = fmaf(xv[f], wo[f],  no_);
                }
                zxi = ni; zxf = nf; zxg = ng; zxo = no_;
            }
        }
    }

    if (k == 0) {
        float acc = bdv;
        acc = fmaf(h0, wd0, acc);
        acc = fmaf(h1, wd1, acc);
        acc = fmaf(h2, wd2, acc);
        const float e = __builtin_amdgcn_exp2f(-LOG2E * acc);
        out[b] = __builtin_amdgcn_rcpf(1.0f + e);
    }
}

extern "C" void kernel_launch(void* const* d_in, const int* in_sizes, int n_in,
                              void* d_out, int out_size, void* d_ws, size_t ws_size,
                              hipStream_t stream) {
    const float* X  = (const float*)d_in[0];
    const float* W  = (const float*)d_in[1];
    const float* U  = (const float*)d_in[2];
    const float* bg = (const float*)d_in[3];
    const float* Wd = (const float*)d_in[4];
    const float* bd = (const float*)d_in[5];
    float* out = (float*)d_out;

    dim3 grid(8192 / 16);   // 512 blocks x 64 threads = 512 waves, 2/CU on all CUs
    dim3 block(64);
    hipLaunchKernelGGL(lstm_unit_kernel, grid, block, 0, stream,
                       X, W, U, bg, Wd, bd, out);
}

// Round 10
// 151.793 us; speedup vs baseline: 1.4533x; 1.4532x over previous
//
#include <hip/hip_runtime.h>

#define LOG2E 1.44269504088896340736f

// ds_swizzle BitMode: src_lane = ((lane & and) | or) ^ xor; imm=(xor<<10)|(or<<5)|and
// Masks 0x01C/0x03C/0x05C proven in R2/R9.
#define SWZ(v, imm) __int_as_float(__builtin_amdgcn_ds_swizzle(__float_as_int(v), (imm)))

typedef __attribute__((address_space(3))) char lds_char_t;
typedef __attribute__((address_space(1))) const char g_char_t;

#define WAITVM(n) asm volatile("s_waitcnt vmcnt(" #n ")" ::: "memory")

// Unit-owner layout (R9-proven): 4 lanes/row, lane k=tid&3 owns unit min(k,2),
// computes all 4 gate columns locally; one swizzle round (h-broadcast) per step.
// NEW: X staged through LDS in 8-step blocks via global_load_lds, double-
// buffered, counted vmcnt(8) once per block -> load latency structurally
// hidden behind a full block of compute. 1 wave/block => no barriers.
// LDS: lane l writes lds[boff + step*1024 + l*16] (= row(l)*64 + quarter*16).
// Reads rotated per-lane: chunk J = quarter (J+row)&3 -> 2-way bank alias (free),
// with weights pre-loaded in matching rotated order.
__global__ __launch_bounds__(64, 1)
void lstm_ldspipe_kernel(const float* __restrict__ X,    // [8192,512,16]
                         const float* __restrict__ Wg,   // [16,12]
                         const float* __restrict__ Ug,   // [3,12]
                         const float* __restrict__ bg,   // [12]
                         const float* __restrict__ Wd,   // [3]
                         const float* __restrict__ bd,   // [1]
                         float* __restrict__ out)        // [8192]
{
    constexpr int T = 512;
    __shared__ __align__(16) char lds[16384];  // 2 bufs x 8 steps x 1KB

    const int tid = threadIdx.x;      // 0..63
    const int r   = tid >> 2;         // row in wave 0..15
    const int k   = tid & 3;          // unit (3 dups 2); also staging quarter
    const int kk  = (k == 3) ? 2 : k;
    const int b   = blockIdx.x * 16 + r;

    const int ci = kk, cf = 3 + kk, cg = 6 + kk, co = 9 + kk;

    // rotated weights: chunk J holds features 4*((J+r)&3)+e
    float wi[16], wf[16], wgt[16], wo[16];
#pragma unroll
    for (int J = 0; J < 4; ++J) {
        const int fbase = ((J + r) & 3) * 4;
#pragma unroll
        for (int e = 0; e < 4; ++e) {
            const float* row = Wg + (size_t)(fbase + e) * 12;
            wi [J*4+e] = row[ci];
            wf [J*4+e] = row[cf];
            wgt[J*4+e] = row[cg];
            wo [J*4+e] = row[co];
        }
    }
    const float ui0 = Ug[ci], ui1 = Ug[12+ci], ui2 = Ug[24+ci];
    const float uf0 = Ug[cf], uf1 = Ug[12+cf], uf2 = Ug[24+cf];
    const float ug0 = Ug[cg], ug1 = Ug[12+cg], ug2 = Ug[24+cg];
    const float uo0 = Ug[co], uo1 = Ug[12+co], uo2 = Ug[24+co];
    const float bias_i = bg[ci], bias_f = bg[cf], bias_g = bg[cg], bias_o = bg[co];
    const float wd0 = Wd[0], wd1 = Wd[1], wd2 = Wd[2], bdv = bd[0];

    const int rot0 = (0 + r) & 3, rot1 = (1 + r) & 3,
              rot2 = (2 + r) & 3, rot3 = (3 + r) & 3;

    float c = 0.f, h0 = 0.f, h1 = 0.f, h2 = 0.f;

    // per-lane global source: (row b, quarter k)
    const float4* Xlane = reinterpret_cast<const float4*>(X)
                          + (size_t)b * (T * 4) + k;

#define STAGE_BLK(tblk, boff) do {                                            \
    const float4* gsrc_ = Xlane + (size_t)(tblk) * 32;                        \
    _Pragma("unroll")                                                         \
    for (int s_ = 0; s_ < 8; ++s_) {                                          \
        lds_char_t* lp_ = (lds_char_t*)(uintptr_t)(lds + (boff) + s_ * 1024); \
        __builtin_amdgcn_global_load_lds((g_char_t*)(const void*)(gsrc_ + s_ * 4), \
                                         lp_, 16, 0, 0);                      \
    }                                                                         \
} while (0)

#define LOAD_XQ(D0, D1, D2, D3, boff, s) do {                                 \
    const float4* lp_ = (const float4*)(lds + (boff) + (s) * 1024 + r * 64);  \
    D0 = lp_[rot0]; D1 = lp_[rot1]; D2 = lp_[rot2]; D3 = lp_[rot3];           \
} while (0)

#define STEP(X0, X1, X2, X3) do {                                             \
    const float xs[16] = {X0.x,X0.y,X0.z,X0.w, X1.x,X1.y,X1.z,X1.w,           \
                          X2.x,X2.y,X2.z,X2.w, X3.x,X3.y,X3.z,X3.w};          \
    float zi = bias_i, zf = bias_f, zg = bias_g, zo = bias_o;                 \
    _Pragma("unroll")                                                         \
    for (int f_ = 0; f_ < 16; ++f_) {                                         \
        zi = fmaf(xs[f_], wi[f_],  zi);                                       \
        zf = fmaf(xs[f_], wf[f_],  zf);                                       \
        zg = fmaf(xs[f_], wgt[f_], zg);                                       \
        zo = fmaf(xs[f_], wo[f_],  zo);                                       \
    }                                                                         \
    zi = fmaf(h0, ui0, zi); zi = fmaf(h1, ui1, zi); zi = fmaf(h2, ui2, zi);   \
    zf = fmaf(h0, uf0, zf); zf = fmaf(h1, uf1, zf); zf = fmaf(h2, uf2, zf);   \
    zg = fmaf(h0, ug0, zg); zg = fmaf(h1, ug1, zg); zg = fmaf(h2, ug2, zg);   \
    zo = fmaf(h0, uo0, zo); zo = fmaf(h1, uo1, zo); zo = fmaf(h2, uo2, zo);   \
    const float ei = __builtin_amdgcn_exp2f(zi * (-LOG2E));                   \
    const float ef = __builtin_amdgcn_exp2f(zf * (-LOG2E));                   \
    const float eg = __builtin_amdgcn_exp2f(zg * (-2.0f * LOG2E));            \
    const float eo = __builtin_amdgcn_exp2f(zo * (-LOG2E));                   \
    const float ai = __builtin_amdgcn_rcpf(1.0f + ei);                        \
    const float af = __builtin_amdgcn_rcpf(1.0f + ef);                        \
    const float ag = fmaf(2.0f, __builtin_amdgcn_rcpf(1.0f + eg), -1.0f);     \
    const float ao = __builtin_amdgcn_rcpf(1.0f + eo);                        \
    c = fmaf(af, c, ai * ag);                                                 \
    const float ec = __builtin_amdgcn_exp2f(c * (-2.0f * LOG2E));             \
    const float th = fmaf(2.0f, __builtin_amdgcn_rcpf(1.0f + ec), -1.0f);     \
    const float hk = ao * th;                                                 \
    h0 = SWZ(hk, 0x01C); h1 = SWZ(hk, 0x03C); h2 = SWZ(hk, 0x05C);            \
} while (0)

    // prologue: two blocks in flight, wait for the first only
    STAGE_BLK(0, 0);
    STAGE_BLK(1, 8192);
    WAITVM(8);
    __builtin_amdgcn_sched_barrier(0);

    float4 xa0, xa1, xa2, xa3, xb0, xb1, xb2, xb3;
    LOAD_XQ(xa0, xa1, xa2, xa3, 0, 0);

    for (int blk = 0; blk < 64; ++blk) {
        const int boff = (blk & 1) ? 8192 : 0;
#pragma unroll
        for (int s = 0; s < 8; ++s) {
            if ((s & 1) == 0) {
                if (s < 7) LOAD_XQ(xb0, xb1, xb2, xb3, boff, s + 1);
                STEP(xa0, xa1, xa2, xa3);
            } else {
                if (s < 7) LOAD_XQ(xa0, xa1, xa2, xa3, boff, s + 1);
                STEP(xb0, xb1, xb2, xb3);
            }
        }
        // all reads of buf[boff] are consumed; safe to overwrite it
        __builtin_amdgcn_sched_barrier(0);
        if (blk + 2 < 64) {
            STAGE_BLK(blk + 2, boff);
            WAITVM(8);   // waits for block blk+1 (issued a full block ago)
        } else {
            WAITVM(0);
        }
        __builtin_amdgcn_sched_barrier(0);
        if (blk < 63) {
            LOAD_XQ(xa0, xa1, xa2, xa3, boff ^ 8192, 0);
        }
    }

    if (k == 0) {
        float acc = bdv;
        acc = fmaf(h0, wd0, acc);
        acc = fmaf(h1, wd1, acc);
        acc = fmaf(h2, wd2, acc);
        const float e = __builtin_amdgcn_exp2f(-LOG2E * acc);
        out[b] = __builtin_amdgcn_rcpf(1.0f + e);
    }
#undef STAGE_BLK
#undef LOAD_XQ
#undef STEP
}

extern "C" void kernel_launch(void* const* d_in, const int* in_sizes, int n_in,
                              void* d_out, int out_size, void* d_ws, size_t ws_size,
                              hipStream_t stream) {
    const float* X  = (const float*)d_in[0];
    const float* W  = (const float*)d_in[1];
    const float* U  = (const float*)d_in[2];
    const float* bg = (const float*)d_in[3];
    const float* Wd = (const float*)d_in[4];
    const float* bd = (const float*)d_in[5];
    float* out = (float*)d_out;

    dim3 grid(8192 / 16);   // 512 blocks x 64 threads (1 wave each)
    dim3 block(64);
    hipLaunchKernelGGL(lstm_ldspipe_kernel, grid, block, 0, stream,
                       X, W, U, bg, Wd, bd, out);
}